// Round 1
// baseline (7904.666 us; speedup 1.0000x reference)
//
#include <hip/hip_runtime.h>

constexpr int NU = 150000;
constexpr int NR = 150000;
constexpr int Hc = 64;
constexpr int UF = 58;
constexpr int RF = 128;
constexpr long EE = 2000000;
constexpr long ELc = 500000;

// ---- edge counts (once; reused by both layers) ----
__global__ void count_kernel(const int* __restrict__ ei,
                             float* __restrict__ cntU, float* __restrict__ cntR) {
    int e = blockIdx.x * blockDim.x + threadIdx.x;
    if (e >= EE) return;
    atomicAdd(&cntU[ei[e]], 1.0f);
    atomicAdd(&cntR[ei[EE + e]], 1.0f);
}

// ---- node encoder: out = x @ W.T + b + emb[nid] ----
template <int F>
__global__ void encode_kernel(const float* __restrict__ xin, const float* __restrict__ w,
                              const float* __restrict__ b, const float* __restrict__ emb,
                              const int* __restrict__ nid, float* __restrict__ out, int N) {
    __shared__ float wT[F * Hc];    // transposed: wT[i*64+o] for conflict-free reads
    __shared__ float xs[4][F];
    __shared__ float bs[Hc];
    for (int idx = threadIdx.x; idx < F * Hc; idx += blockDim.x) {
        int o = idx / F, i = idx % F;
        wT[i * Hc + o] = w[idx];
    }
    if (threadIdx.x < Hc) bs[threadIdx.x] = b[threadIdx.x];
    __syncthreads();
    int g = threadIdx.x >> 6, t = threadIdx.x & 63;
    int stride = gridDim.x * 4;
    for (int rb = blockIdx.x * 4; rb < N; rb += stride) {  // uniform trip count
        int r = rb + g;
        bool valid = r < N;
        if (valid) {
            for (int i = t; i < F; i += 64) xs[g][i] = xin[(long)r * F + i];
        }
        __syncthreads();
        if (valid) {
            float acc = bs[t];
#pragma unroll 8
            for (int k = 0; k < F; ++k) acc += xs[g][k] * wT[k * Hc + t];
            acc += emb[(long)nid[r] * Hc + t];
            out[(long)r * Hc + t] = acc;
        }
        __syncthreads();
    }
}

// ---- fused bidirectional mean-aggregation scatter over edges ----
__global__ void scatter_kernel(const int* __restrict__ ei,
                               const float* __restrict__ XU_, const float* __restrict__ XR_,
                               float* __restrict__ SR_, float* __restrict__ SU_) {
    long gid = (long)blockIdx.x * blockDim.x + threadIdx.x;
    long e = gid >> 4;
    int t = (int)(gid & 15);
    if (e >= EE) return;
    int s = ei[e], d = ei[EE + e];
    float4 a = *(const float4*)(XU_ + (long)s * Hc + t * 4);
    float* pr = SR_ + (long)d * Hc + t * 4;
    atomicAdd(pr + 0, a.x); atomicAdd(pr + 1, a.y);
    atomicAdd(pr + 2, a.z); atomicAdd(pr + 3, a.w);
    float4 c = *(const float4*)(XR_ + (long)d * Hc + t * 4);
    float* pu = SU_ + (long)s * Hc + t * 4;
    atomicAdd(pu + 0, c.x); atomicAdd(pu + 1, c.y);
    atomicAdd(pu + 2, c.z); atomicAdd(pu + 3, c.w);
}

// ---- out = (S/max(cnt,1)) @ wl.T + bl + xd @ wr.T  (+ optional relu) ----
__global__ void mean_lin_kernel(const float* __restrict__ S, const float* __restrict__ cnt,
                                const float* __restrict__ xd,
                                const float* __restrict__ wl, const float* __restrict__ bl,
                                const float* __restrict__ wr,
                                float* __restrict__ out, int N, int relu) {
    __shared__ float wlT[Hc * Hc];
    __shared__ float wrT[Hc * Hc];
    __shared__ float bls[Hc];
    __shared__ float ms[4][Hc];
    __shared__ float xs[4][Hc];
    for (int idx = threadIdx.x; idx < Hc * Hc; idx += blockDim.x) {
        int o = idx >> 6, i = idx & 63;
        wlT[i * Hc + o] = wl[idx];
        wrT[i * Hc + o] = wr[idx];
    }
    if (threadIdx.x < Hc) bls[threadIdx.x] = bl[threadIdx.x];
    __syncthreads();
    int g = threadIdx.x >> 6, t = threadIdx.x & 63;
    int stride = gridDim.x * 4;
    for (int rb = blockIdx.x * 4; rb < N; rb += stride) {
        int r = rb + g;
        bool valid = r < N;
        if (valid) {
            float inv = 1.0f / fmaxf(cnt[r], 1.0f);
            ms[g][t] = S[(long)r * Hc + t] * inv;
            xs[g][t] = xd[(long)r * Hc + t];
        }
        __syncthreads();
        if (valid) {
            float acc = bls[t];
#pragma unroll 8
            for (int k = 0; k < Hc; ++k)
                acc += ms[g][k] * wlT[k * Hc + t] + xs[g][k] * wrT[k * Hc + t];
            if (relu) acc = fmaxf(acc, 0.0f);
            out[(long)r * Hc + t] = acc;
        }
        __syncthreads();
    }
}

// ---- edge dot-product classifier ----
__global__ void edge_dot_kernel(const int* __restrict__ eli,
                                const float* __restrict__ HU2, const float* __restrict__ HR2,
                                float* __restrict__ out) {
    long gid = (long)blockIdx.x * blockDim.x + threadIdx.x;
    long e = gid >> 4;
    int t = (int)(gid & 15);
    if (e >= ELc) return;
    int a = eli[e], b = eli[ELc + e];
    float4 x = *(const float4*)(HU2 + (long)a * Hc + t * 4);
    float4 y = *(const float4*)(HR2 + (long)b * Hc + t * 4);
    float v = x.x * y.x + x.y * y.y + x.z * y.z + x.w * y.w;
    v += __shfl_xor(v, 1);
    v += __shfl_xor(v, 2);
    v += __shfl_xor(v, 4);
    v += __shfl_xor(v, 8);
    if (t == 0) out[e] = v;
}

extern "C" void kernel_launch(void* const* d_in, const int* in_sizes, int n_in,
                              void* d_out, int out_size, void* d_ws, size_t ws_size,
                              hipStream_t stream) {
    const float* x_user   = (const float*)d_in[0];
    const float* x_recipe = (const float*)d_in[1];
    const int*   user_nid = (const int*)d_in[2];
    const int*   rec_nid  = (const int*)d_in[3];
    const int*   edge_index = (const int*)d_in[4];
    const int*   edge_label = (const int*)d_in[5];
    const float* u_w   = (const float*)d_in[6];
    const float* u_b   = (const float*)d_in[7];
    const float* r_w   = (const float*)d_in[8];
    const float* r_b   = (const float*)d_in[9];
    const float* u_emb = (const float*)d_in[10];
    const float* r_emb = (const float*)d_in[11];
    const float* c1ra_wl = (const float*)d_in[12];
    const float* c1ra_bl = (const float*)d_in[13];
    const float* c1ra_wr = (const float*)d_in[14];
    const float* c1rv_wl = (const float*)d_in[15];
    const float* c1rv_bl = (const float*)d_in[16];
    const float* c1rv_wr = (const float*)d_in[17];
    const float* c2ra_wl = (const float*)d_in[18];
    const float* c2ra_bl = (const float*)d_in[19];
    const float* c2ra_wr = (const float*)d_in[20];
    const float* c2rv_wl = (const float*)d_in[21];
    const float* c2rv_bl = (const float*)d_in[22];
    const float* c2rv_wr = (const float*)d_in[23];

    float* ws = (float*)d_ws;
    const long NH = (long)NU * Hc;   // == NR*Hc
    float* XU = ws;            // user enc, later reused for HR2
    float* XR = XU + NH;       // recipe enc, later reused for HU2
    float* HR = XR + NH;
    float* HU = HR + NH;
    float* SR = HU + NH;       // scatter sums (recipe dst)
    float* SU = SR + NH;       // scatter sums (user dst)
    float* cntR = SU + NH;
    float* cntU = cntR + NR;

    // zero accumulators + counts (SR,SU contiguous; cntR,cntU contiguous)
    hipMemsetAsync(SR, 0, (size_t)2 * NH * sizeof(float), stream);
    hipMemsetAsync(cntR, 0, (size_t)(NR + NU) * sizeof(float), stream);

    count_kernel<<<(EE + 255) / 256, 256, 0, stream>>>(edge_index, cntU, cntR);
    encode_kernel<UF><<<2048, 256, 0, stream>>>(x_user, u_w, u_b, u_emb, user_nid, XU, NU);
    encode_kernel<RF><<<2048, 256, 0, stream>>>(x_recipe, r_w, r_b, r_emb, rec_nid, XR, NR);

    // layer 1
    scatter_kernel<<<(EE * 16) / 256, 256, 0, stream>>>(edge_index, XU, XR, SR, SU);
    mean_lin_kernel<<<2048, 256, 0, stream>>>(SR, cntR, XR, c1ra_wl, c1ra_bl, c1ra_wr, HR, NR, 1);
    mean_lin_kernel<<<2048, 256, 0, stream>>>(SU, cntU, XU, c1rv_wl, c1rv_bl, c1rv_wr, HU, NU, 1);

    // layer 2
    hipMemsetAsync(SR, 0, (size_t)2 * NH * sizeof(float), stream);
    scatter_kernel<<<(EE * 16) / 256, 256, 0, stream>>>(edge_index, HU, HR, SR, SU);
    mean_lin_kernel<<<2048, 256, 0, stream>>>(SR, cntR, HR, c2ra_wl, c2ra_bl, c2ra_wr, XU, NR, 0); // HR2 -> XU buf
    mean_lin_kernel<<<2048, 256, 0, stream>>>(SU, cntU, HU, c2rv_wl, c2rv_bl, c2rv_wr, XR, NU, 0); // HU2 -> XR buf

    // classifier: eli[0]=user -> HU2(XR), eli[1]=recipe -> HR2(XU)
    edge_dot_kernel<<<(ELc * 16) / 256, 256, 0, stream>>>(edge_label, XR, XU, (float*)d_out);
}

// Round 2
// 3278.610 us; speedup vs baseline: 2.4110x; 2.4110x over previous
//
#include <hip/hip_runtime.h>

constexpr int NU = 150000;
constexpr int NR = 150000;
constexpr int Hc = 64;
constexpr int UF = 58;
constexpr int RF = 128;
constexpr long EE = 2000000;
constexpr long ELc = 500000;
constexpr int NTOT = NU + NR;           // combined node space: [0,NR)=recipes, [NR,NTOT)=users
constexpr int SCAN_B = 512;
constexpr int NBLK = (NTOT + SCAN_B - 1) / SCAN_B;   // 586

// ---- int degree counts over combined node space ----
__global__ void counti_kernel(const int* __restrict__ ei, int* __restrict__ cnt) {
    long e = (long)blockIdx.x * blockDim.x + threadIdx.x;
    if (e >= EE) return;
    atomicAdd(&cnt[ei[EE + e]], 1);        // recipe dst at [r]
    atomicAdd(&cnt[NR + ei[e]], 1);        // user src at [NR+u]
}

// ---- 3-kernel exclusive scan over NTOT ints ----
__global__ void scan1_kernel(const int* __restrict__ cnt, int* __restrict__ exc,
                             int* __restrict__ partial) {
    __shared__ int s[SCAN_B];
    int i = blockIdx.x * SCAN_B + threadIdx.x;
    int v = (i < NTOT) ? cnt[i] : 0;
    s[threadIdx.x] = v;
    __syncthreads();
    for (int off = 1; off < SCAN_B; off <<= 1) {
        int t = (threadIdx.x >= off) ? s[threadIdx.x - off] : 0;
        __syncthreads();
        s[threadIdx.x] += t;
        __syncthreads();
    }
    if (i < NTOT) exc[i] = s[threadIdx.x] - v;        // exclusive within block
    if (threadIdx.x == SCAN_B - 1) partial[blockIdx.x] = s[SCAN_B - 1];
}

__global__ void scan2_kernel(int* __restrict__ partial) {
    __shared__ int s[1024];
    int v = (threadIdx.x < NBLK) ? partial[threadIdx.x] : 0;
    s[threadIdx.x] = v;
    __syncthreads();
    for (int off = 1; off < 1024; off <<= 1) {
        int t = (threadIdx.x >= off) ? s[threadIdx.x - off] : 0;
        __syncthreads();
        s[threadIdx.x] += t;
        __syncthreads();
    }
    if (threadIdx.x < NBLK) partial[threadIdx.x] = s[threadIdx.x] - v;  // exclusive
}

__global__ void scan3_kernel(int* __restrict__ exc, const int* __restrict__ partial,
                             int* __restrict__ cur) {
    int i = blockIdx.x * SCAN_B + threadIdx.x;
    if (i < NTOT) {
        int b = exc[i] + partial[blockIdx.x];
        exc[i] = b;       // base offsets
        cur[i] = b;       // fill cursors
    }
}

// ---- CSR fill: adj[0..2M) recipe-side (stores user src), [2M..4M) user-side ----
__global__ void fill_kernel(const int* __restrict__ ei, int* __restrict__ cur,
                            int* __restrict__ adj) {
    long e = (long)blockIdx.x * blockDim.x + threadIdx.x;
    if (e >= EE) return;
    int u = ei[e], r = ei[EE + e];
    int pr = atomicAdd(&cur[r], 1);
    adj[pr] = u;
    int pu = atomicAdd(&cur[NR + u], 1);
    adj[pu] = r;
}

// ---- node encoder: out = x @ W.T + b + emb[nid] ----
template <int F>
__global__ void encode_kernel(const float* __restrict__ xin, const float* __restrict__ w,
                              const float* __restrict__ b, const float* __restrict__ emb,
                              const int* __restrict__ nid, float* __restrict__ out, int N) {
    __shared__ float wT[F * Hc];
    __shared__ float xs[4][F];
    __shared__ float bs[Hc];
    for (int idx = threadIdx.x; idx < F * Hc; idx += blockDim.x) {
        int o = idx / F, i = idx % F;
        wT[i * Hc + o] = w[idx];
    }
    if (threadIdx.x < Hc) bs[threadIdx.x] = b[threadIdx.x];
    __syncthreads();
    int g = threadIdx.x >> 6, t = threadIdx.x & 63;
    int stride = gridDim.x * 4;
    for (int rb = blockIdx.x * 4; rb < N; rb += stride) {
        int r = rb + g;
        bool valid = r < N;
        if (valid) {
            for (int i = t; i < F; i += 64) xs[g][i] = xin[(long)r * F + i];
        }
        __syncthreads();
        if (valid) {
            float acc = bs[t];
#pragma unroll 8
            for (int k = 0; k < F; ++k) acc += xs[g][k] * wT[k * Hc + t];
            acc += emb[(long)nid[r] * Hc + t];
            out[(long)r * Hc + t] = acc;
        }
        __syncthreads();
    }
}

// ---- fused: mean-aggregate (gather via CSR) + lin_l + lin_r + optional relu ----
__global__ void sage_kernel(const float* __restrict__ Xsrc, const float* __restrict__ Xdst,
                            const int* __restrict__ base, const int* __restrict__ cnt,
                            const int* __restrict__ adj, int nodeoff,
                            const float* __restrict__ wl, const float* __restrict__ bl,
                            const float* __restrict__ wr,
                            float* __restrict__ out, int N, int relu) {
    __shared__ float wlT[Hc * Hc];
    __shared__ float wrT[Hc * Hc];
    __shared__ float bls[Hc];
    __shared__ float ms[4][Hc];
    __shared__ float xs[4][Hc];
    for (int idx = threadIdx.x; idx < Hc * Hc; idx += blockDim.x) {
        int o = idx >> 6, i = idx & 63;
        wlT[i * Hc + o] = wl[idx];
        wrT[i * Hc + o] = wr[idx];
    }
    if (threadIdx.x < Hc) bls[threadIdx.x] = bl[threadIdx.x];
    __syncthreads();
    int g = threadIdx.x >> 6, t = threadIdx.x & 63;
    int r = blockIdx.x * 4 + g;
    bool valid = r < N;
    if (valid) {
        int b0 = base[nodeoff + r], c = cnt[nodeoff + r];
        float acc = 0.0f;
        int j = 0;
        for (; j + 4 <= c; j += 4) {
            int n0 = adj[b0 + j], n1 = adj[b0 + j + 1];
            int n2 = adj[b0 + j + 2], n3 = adj[b0 + j + 3];
            acc += Xsrc[(long)n0 * Hc + t] + Xsrc[(long)n1 * Hc + t]
                 + Xsrc[(long)n2 * Hc + t] + Xsrc[(long)n3 * Hc + t];
        }
        for (; j < c; ++j) acc += Xsrc[(long)adj[b0 + j] * Hc + t];
        ms[g][t] = acc / fmaxf((float)c, 1.0f);
        xs[g][t] = Xdst[(long)r * Hc + t];
    }
    __syncthreads();
    if (valid) {
        float a2 = bls[t];
#pragma unroll 8
        for (int k = 0; k < Hc; ++k)
            a2 += ms[g][k] * wlT[k * Hc + t] + xs[g][k] * wrT[k * Hc + t];
        if (relu) a2 = fmaxf(a2, 0.0f);
        out[(long)r * Hc + t] = a2;
    }
}

// ---- edge dot-product classifier ----
__global__ void edge_dot_kernel(const int* __restrict__ eli,
                                const float* __restrict__ HU2, const float* __restrict__ HR2,
                                float* __restrict__ out) {
    long gid = (long)blockIdx.x * blockDim.x + threadIdx.x;
    long e = gid >> 4;
    int t = (int)(gid & 15);
    if (e >= ELc) return;
    int a = eli[e], b = eli[ELc + e];
    float4 x = *(const float4*)(HU2 + (long)a * Hc + t * 4);
    float4 y = *(const float4*)(HR2 + (long)b * Hc + t * 4);
    float v = x.x * y.x + x.y * y.y + x.z * y.z + x.w * y.w;
    v += __shfl_xor(v, 1);
    v += __shfl_xor(v, 2);
    v += __shfl_xor(v, 4);
    v += __shfl_xor(v, 8);
    if (t == 0) out[e] = v;
}

extern "C" void kernel_launch(void* const* d_in, const int* in_sizes, int n_in,
                              void* d_out, int out_size, void* d_ws, size_t ws_size,
                              hipStream_t stream) {
    const float* x_user   = (const float*)d_in[0];
    const float* x_recipe = (const float*)d_in[1];
    const int*   user_nid = (const int*)d_in[2];
    const int*   rec_nid  = (const int*)d_in[3];
    const int*   edge_index = (const int*)d_in[4];
    const int*   edge_label = (const int*)d_in[5];
    const float* u_w   = (const float*)d_in[6];
    const float* u_b   = (const float*)d_in[7];
    const float* r_w   = (const float*)d_in[8];
    const float* r_b   = (const float*)d_in[9];
    const float* u_emb = (const float*)d_in[10];
    const float* r_emb = (const float*)d_in[11];
    const float* c1ra_wl = (const float*)d_in[12];
    const float* c1ra_bl = (const float*)d_in[13];
    const float* c1ra_wr = (const float*)d_in[14];
    const float* c1rv_wl = (const float*)d_in[15];
    const float* c1rv_bl = (const float*)d_in[16];
    const float* c1rv_wr = (const float*)d_in[17];
    const float* c2ra_wl = (const float*)d_in[18];
    const float* c2ra_bl = (const float*)d_in[19];
    const float* c2ra_wr = (const float*)d_in[20];
    const float* c2rv_wl = (const float*)d_in[21];
    const float* c2rv_bl = (const float*)d_in[22];
    const float* c2rv_wr = (const float*)d_in[23];

    float* ws = (float*)d_ws;
    const long NH = (long)NU * Hc;
    float* XU = ws;            // user enc; later reused for HR2
    float* XR = XU + NH;       // recipe enc; later reused for HU2
    float* HR = XR + NH;
    float* HU = HR + NH;
    int* ip   = (int*)(HU + NH);
    int* cnt  = ip;                  // [NTOT]
    int* base = cnt + NTOT;          // [NTOT]
    int* cur  = base + NTOT;         // [NTOT]
    int* partial = cur + NTOT;       // [1024]
    int* adj  = partial + 1024;      // [2*EE]

    // ---- CSR build (once; reused by both layers) ----
    hipMemsetAsync(cnt, 0, (size_t)NTOT * sizeof(int), stream);
    counti_kernel<<<(EE + 255) / 256, 256, 0, stream>>>(edge_index, cnt);
    scan1_kernel<<<NBLK, SCAN_B, 0, stream>>>(cnt, base, partial);
    scan2_kernel<<<1, 1024, 0, stream>>>(partial);
    scan3_kernel<<<NBLK, SCAN_B, 0, stream>>>(base, partial, cur);
    fill_kernel<<<(EE + 255) / 256, 256, 0, stream>>>(edge_index, cur, adj);

    // ---- encoders ----
    encode_kernel<UF><<<2048, 256, 0, stream>>>(x_user, u_w, u_b, u_emb, user_nid, XU, NU);
    encode_kernel<RF><<<2048, 256, 0, stream>>>(x_recipe, r_w, r_b, r_emb, rec_nid, XR, NR);

    const int GB = (NU + 3) / 4;   // blocks for 4 rows each
    // ---- layer 1 ----
    sage_kernel<<<GB, 256, 0, stream>>>(XU, XR, base, cnt, adj, 0,  c1ra_wl, c1ra_bl, c1ra_wr, HR, NR, 1);
    sage_kernel<<<GB, 256, 0, stream>>>(XR, XU, base, cnt, adj, NR, c1rv_wl, c1rv_bl, c1rv_wr, HU, NU, 1);
    // ---- layer 2 (outputs reuse XU/XR buffers) ----
    sage_kernel<<<GB, 256, 0, stream>>>(HU, HR, base, cnt, adj, 0,  c2ra_wl, c2ra_bl, c2ra_wr, XU, NR, 0); // HR2
    sage_kernel<<<GB, 256, 0, stream>>>(HR, HU, base, cnt, adj, NR, c2rv_wl, c2rv_bl, c2rv_wr, XR, NU, 0); // HU2

    // ---- classifier: eli[0]=user -> HU2(XR), eli[1]=recipe -> HR2(XU) ----
    edge_dot_kernel<<<(ELc * 16) / 256, 256, 0, stream>>>(edge_label, XR, XU, (float*)d_out);
}

// Round 3
// 1603.830 us; speedup vs baseline: 4.9286x; 2.0442x over previous
//
#include <hip/hip_runtime.h>

constexpr int NU = 150000;
constexpr int NR = 150000;
constexpr int Hc = 64;
constexpr int UF = 58;
constexpr int RF = 128;
constexpr long EE = 2000000;
constexpr long ELc = 500000;
constexpr int NTOT = NU + NR;           // [0,NR)=recipes, [NR,NTOT)=users
constexpr int SCAN_B = 512;
constexpr int NBLK = (NTOT + SCAN_B - 1) / SCAN_B;   // 586

__device__ inline float rdlane(float v, int l) {
    return __uint_as_float(__builtin_amdgcn_readlane(__float_as_uint(v), l));
}

// ---- weight pre-transpose: d[k*64+o] = s[o*F+k] (10 small matrices) ----
struct TP { const float* s; float* d; int F; };
struct TP10 { TP m[10]; };
__global__ void transpose_kernel(TP10 p) {
    TP t = p.m[blockIdx.x];
    for (int idx = threadIdx.x; idx < t.F * Hc; idx += blockDim.x) {
        int k = idx >> 6, o = idx & 63;
        t.d[idx] = t.s[o * t.F + k];
    }
}

// ---- int degree counts over combined node space ----
__global__ void counti_kernel(const int* __restrict__ ei, int* __restrict__ cnt) {
    long e = (long)blockIdx.x * blockDim.x + threadIdx.x;
    if (e >= EE) return;
    atomicAdd(&cnt[ei[EE + e]], 1);
    atomicAdd(&cnt[NR + ei[e]], 1);
}

// ---- 3-kernel exclusive scan ----
__global__ void scan1_kernel(const int* __restrict__ cnt, int* __restrict__ exc,
                             int* __restrict__ partial) {
    __shared__ int s[SCAN_B];
    int i = blockIdx.x * SCAN_B + threadIdx.x;
    int v = (i < NTOT) ? cnt[i] : 0;
    s[threadIdx.x] = v;
    __syncthreads();
    for (int off = 1; off < SCAN_B; off <<= 1) {
        int t = (threadIdx.x >= off) ? s[threadIdx.x - off] : 0;
        __syncthreads();
        s[threadIdx.x] += t;
        __syncthreads();
    }
    if (i < NTOT) exc[i] = s[threadIdx.x] - v;
    if (threadIdx.x == SCAN_B - 1) partial[blockIdx.x] = s[SCAN_B - 1];
}

__global__ void scan2_kernel(int* __restrict__ partial) {
    __shared__ int s[1024];
    int v = (threadIdx.x < NBLK) ? partial[threadIdx.x] : 0;
    s[threadIdx.x] = v;
    __syncthreads();
    for (int off = 1; off < 1024; off <<= 1) {
        int t = (threadIdx.x >= off) ? s[threadIdx.x - off] : 0;
        __syncthreads();
        s[threadIdx.x] += t;
        __syncthreads();
    }
    if (threadIdx.x < NBLK) partial[threadIdx.x] = s[threadIdx.x] - v;
}

__global__ void scan3_kernel(int* __restrict__ exc, const int* __restrict__ partial,
                             int* __restrict__ cur) {
    int i = blockIdx.x * SCAN_B + threadIdx.x;
    if (i < NTOT) {
        int b = exc[i] + partial[blockIdx.x];
        exc[i] = b;
        cur[i] = b;
    }
}

__global__ void fill_kernel(const int* __restrict__ ei, int* __restrict__ cur,
                            int* __restrict__ adj) {
    long e = (long)blockIdx.x * blockDim.x + threadIdx.x;
    if (e >= EE) return;
    int u = ei[e], r = ei[EE + e];
    adj[atomicAdd(&cur[r], 1)] = u;
    adj[atomicAdd(&cur[NR + u], 1)] = r;
}

// ---- node encoder: wave-per-row, weights in registers ----
template <int F>
__global__ __launch_bounds__(256, 2) void encode_kernel(
        const float* __restrict__ xin, const float* __restrict__ wT,
        const float* __restrict__ b, const float* __restrict__ emb,
        const int* __restrict__ nid, float* __restrict__ out, int N) {
    int t = threadIdx.x & 63;
    int wave = (int)((blockIdx.x * blockDim.x + threadIdx.x) >> 6);
    int nwaves = (gridDim.x * blockDim.x) >> 6;
    float wreg[F];
#pragma unroll
    for (int k = 0; k < F; ++k) wreg[k] = wT[k * Hc + t];
    float bv = b[t];
    for (int r = wave; r < N; r += nwaves) {
        float xv0 = (t < F) ? xin[(long)r * F + t] : 0.0f;
        float xv1 = (F > 64) ? xin[(long)r * F + 64 + t] : 0.0f;
        float acc = bv;
#pragma unroll
        for (int k = 0; k < F; ++k) {
            float s = (k < 64) ? rdlane(xv0, k) : rdlane(xv1, k - 64);
            acc = fmaf(s, wreg[k], acc);
        }
        acc += emb[(long)nid[r] * Hc + t];
        out[(long)r * Hc + t] = acc;
    }
}

// ---- fused SAGE: wave-per-row CSR gather + register matvec ----
__global__ __launch_bounds__(256, 2) void sage_kernel(
        const float* __restrict__ Xsrc, const float* __restrict__ Xdst,
        const int* __restrict__ base, const int* __restrict__ cnt,
        const int* __restrict__ adj, int nodeoff,
        const float* __restrict__ wlT, const float* __restrict__ bl,
        const float* __restrict__ wrT,
        float* __restrict__ out, int N, int relu) {
    int t = threadIdx.x & 63;
    int wave = (int)((blockIdx.x * blockDim.x + threadIdx.x) >> 6);
    int nwaves = (gridDim.x * blockDim.x) >> 6;
    float wl_[Hc], wr_[Hc];
#pragma unroll
    for (int k = 0; k < Hc; ++k) {
        wl_[k] = wlT[k * Hc + t];
        wr_[k] = wrT[k * Hc + t];
    }
    float bv = bl[t];
    for (int r = wave; r < N; r += nwaves) {
        int b0 = base[nodeoff + r], c = cnt[nodeoff + r];
        float s = 0.0f;
        int j = 0;
        for (; j + 4 <= c; j += 4) {
            int n0 = adj[b0 + j], n1 = adj[b0 + j + 1];
            int n2 = adj[b0 + j + 2], n3 = adj[b0 + j + 3];
            s += Xsrc[(long)n0 * Hc + t] + Xsrc[(long)n1 * Hc + t]
               + Xsrc[(long)n2 * Hc + t] + Xsrc[(long)n3 * Hc + t];
        }
        for (; j < c; ++j) s += Xsrc[(long)adj[b0 + j] * Hc + t];
        float msv = s / fmaxf((float)c, 1.0f);
        float xdv = Xdst[(long)r * Hc + t];
        float accl = bv, accr = 0.0f;
#pragma unroll
        for (int k = 0; k < Hc; ++k) {
            accl = fmaf(rdlane(msv, k), wl_[k], accl);
            accr = fmaf(rdlane(xdv, k), wr_[k], accr);
        }
        float o = accl + accr;
        if (relu) o = fmaxf(o, 0.0f);
        out[(long)r * Hc + t] = o;
    }
}

// ---- edge dot-product classifier ----
__global__ void edge_dot_kernel(const int* __restrict__ eli,
                                const float* __restrict__ HU2, const float* __restrict__ HR2,
                                float* __restrict__ out) {
    long gid = (long)blockIdx.x * blockDim.x + threadIdx.x;
    long e = gid >> 4;
    int t = (int)(gid & 15);
    if (e >= ELc) return;
    int a = eli[e], b = eli[ELc + e];
    float4 x = *(const float4*)(HU2 + (long)a * Hc + t * 4);
    float4 y = *(const float4*)(HR2 + (long)b * Hc + t * 4);
    float v = x.x * y.x + x.y * y.y + x.z * y.z + x.w * y.w;
    v += __shfl_xor(v, 1);
    v += __shfl_xor(v, 2);
    v += __shfl_xor(v, 4);
    v += __shfl_xor(v, 8);
    if (t == 0) out[e] = v;
}

extern "C" void kernel_launch(void* const* d_in, const int* in_sizes, int n_in,
                              void* d_out, int out_size, void* d_ws, size_t ws_size,
                              hipStream_t stream) {
    const float* x_user   = (const float*)d_in[0];
    const float* x_recipe = (const float*)d_in[1];
    const int*   user_nid = (const int*)d_in[2];
    const int*   rec_nid  = (const int*)d_in[3];
    const int*   edge_index = (const int*)d_in[4];
    const int*   edge_label = (const int*)d_in[5];
    const float* u_w   = (const float*)d_in[6];
    const float* u_b   = (const float*)d_in[7];
    const float* r_w   = (const float*)d_in[8];
    const float* r_b   = (const float*)d_in[9];
    const float* u_emb = (const float*)d_in[10];
    const float* r_emb = (const float*)d_in[11];
    const float* c1ra_wl = (const float*)d_in[12];
    const float* c1ra_bl = (const float*)d_in[13];
    const float* c1ra_wr = (const float*)d_in[14];
    const float* c1rv_wl = (const float*)d_in[15];
    const float* c1rv_bl = (const float*)d_in[16];
    const float* c1rv_wr = (const float*)d_in[17];
    const float* c2ra_wl = (const float*)d_in[18];
    const float* c2ra_bl = (const float*)d_in[19];
    const float* c2ra_wr = (const float*)d_in[20];
    const float* c2rv_wl = (const float*)d_in[21];
    const float* c2rv_bl = (const float*)d_in[22];
    const float* c2rv_wr = (const float*)d_in[23];

    float* ws = (float*)d_ws;
    const long NH = (long)NU * Hc;
    float* XU = ws;            // user enc; later reused for HR2
    float* XR = XU + NH;       // recipe enc; later reused for HU2
    float* HR = XR + NH;
    float* HU = HR + NH;
    int* cnt  = (int*)(HU + NH);     // [NTOT]
    int* base = cnt + NTOT;          // [NTOT]
    int* cur  = base + NTOT;         // [NTOT]
    int* partial = cur + NTOT;       // [1024]
    int* adj  = partial + 1024;      // [2*EE]
    float* wts = (float*)(adj + 2 * EE);
    float* uwT = wts;                // 58*64
    float* rwT = uwT + UF * Hc;      // 128*64
    float* cT[8];                    // 8 x 64*64
    cT[0] = rwT + RF * Hc;
    for (int i = 1; i < 8; ++i) cT[i] = cT[i - 1] + Hc * Hc;

    // ---- weight transposes (once) ----
    TP10 tp;
    tp.m[0] = {u_w, uwT, UF};
    tp.m[1] = {r_w, rwT, RF};
    const float* srcs[8] = {c1ra_wl, c1ra_wr, c1rv_wl, c1rv_wr,
                            c2ra_wl, c2ra_wr, c2rv_wl, c2rv_wr};
    for (int i = 0; i < 8; ++i) tp.m[2 + i] = {srcs[i], cT[i], Hc};
    transpose_kernel<<<10, 256, 0, stream>>>(tp);

    // ---- CSR build (once) ----
    hipMemsetAsync(cnt, 0, (size_t)NTOT * sizeof(int), stream);
    counti_kernel<<<(EE + 255) / 256, 256, 0, stream>>>(edge_index, cnt);
    scan1_kernel<<<NBLK, SCAN_B, 0, stream>>>(cnt, base, partial);
    scan2_kernel<<<1, 1024, 0, stream>>>(partial);
    scan3_kernel<<<NBLK, SCAN_B, 0, stream>>>(base, partial, cur);
    fill_kernel<<<(EE + 255) / 256, 256, 0, stream>>>(edge_index, cur, adj);

    // ---- encoders ----
    encode_kernel<UF><<<2048, 256, 0, stream>>>(x_user, uwT, u_b, u_emb, user_nid, XU, NU);
    encode_kernel<RF><<<2048, 256, 0, stream>>>(x_recipe, rwT, r_b, r_emb, rec_nid, XR, NR);

    // ---- layer 1 ----
    sage_kernel<<<2048, 256, 0, stream>>>(XU, XR, base, cnt, adj, 0,  cT[0], c1ra_bl, cT[1], HR, NR, 1);
    sage_kernel<<<2048, 256, 0, stream>>>(XR, XU, base, cnt, adj, NR, cT[2], c1rv_bl, cT[3], HU, NU, 1);
    // ---- layer 2 ----
    sage_kernel<<<2048, 256, 0, stream>>>(HU, HR, base, cnt, adj, 0,  cT[4], c2ra_bl, cT[5], XU, NR, 0); // HR2
    sage_kernel<<<2048, 256, 0, stream>>>(HR, HU, base, cnt, adj, NR, cT[6], c2rv_bl, cT[7], XR, NU, 0); // HU2

    // ---- classifier: eli[0]=user -> HU2(XR), eli[1]=recipe -> HR2(XU) ----
    edge_dot_kernel<<<(ELc * 16) / 256, 256, 0, stream>>>(edge_label, XR, XU, (float*)d_out);
}

// Round 4
// 1186.664 us; speedup vs baseline: 6.6613x; 1.3515x over previous
//
#include <hip/hip_runtime.h>

constexpr int NU = 150000;
constexpr int NR = 150000;
constexpr int Hc = 64;
constexpr int UF = 58;
constexpr int RF = 128;
constexpr long EE = 2000000;
constexpr long ELc = 500000;
constexpr int NTOT = NU + NR;            // combined ids: [0,NR)=recipes, [NR,NTOT)=users
constexpr int BKT = 256;                 // nodes per bucket
constexpr int NB_R = (NR + BKT - 1) / BKT;   // 586
constexpr int NB_U = (NU + BKT - 1) / BKT;   // 586
constexpr int NBKT = NB_R + NB_U;            // 1172
constexpr int CHUNK = 4096;
constexpr int NCHUNK = (int)((EE + CHUNK - 1) / CHUNK);  // 489

__device__ inline float rdlane(float v, int l) {
    return __uint_as_float(__builtin_amdgcn_readlane(__float_as_uint(v), l));
}

// ---- weight pre-transpose: d[k*64+o] = s[o*F+k] (10 small matrices) ----
struct TP { const float* s; float* d; int F; };
struct TP10 { TP m[10]; };
__global__ void transpose_kernel(TP10 p) {
    TP t = p.m[blockIdx.x];
    for (int idx = threadIdx.x; idx < t.F * Hc; idx += blockDim.x) {
        int k = idx >> 6, o = idx & 63;
        t.d[idx] = t.s[o * t.F + k];
    }
}

// ---- CSR build, pass 0: per-bucket edge counts (LDS-binned) ----
__global__ void bucket_count_kernel(const int* __restrict__ ei, int* __restrict__ bcnt) {
    __shared__ int lc[NBKT];
    for (int i = threadIdx.x; i < NBKT; i += 256) lc[i] = 0;
    __syncthreads();
    long e0 = (long)blockIdx.x * CHUNK;
    for (int k = threadIdx.x; k < CHUNK; k += 256) {
        long e = e0 + k;
        if (e < EE) {
            int u = ei[e], r = ei[EE + e];
            atomicAdd(&lc[r >> 8], 1);
            atomicAdd(&lc[NB_R + (u >> 8)], 1);
        }
    }
    __syncthreads();
    for (int i = threadIdx.x; i < NBKT; i += 256)
        if (lc[i]) atomicAdd(&bcnt[i], lc[i]);
}

// ---- pass 1: exclusive scan over NBKT bucket counts (single block) ----
__global__ void bucket_scan_kernel(const int* __restrict__ bcnt, int* __restrict__ bbase,
                                   int* __restrict__ bcur) {
    __shared__ int part[256];
    constexpr int PER = (NBKT + 255) / 256;   // 5
    int t = threadIdx.x;
    int loc[PER];
    int sum = 0;
    for (int j = 0; j < PER; ++j) {
        int i = t * PER + j;
        int v = (i < NBKT) ? bcnt[i] : 0;
        loc[j] = sum;
        sum += v;
    }
    part[t] = sum;
    __syncthreads();
    for (int off = 1; off < 256; off <<= 1) {
        int v = (t >= off) ? part[t - off] : 0;
        __syncthreads();
        part[t] += v;
        __syncthreads();
    }
    int pre = (t == 0) ? 0 : part[t - 1];
    for (int j = 0; j < PER; ++j) {
        int i = t * PER + j;
        if (i < NBKT) {
            int b = pre + loc[j];
            bbase[i] = b;
            bcur[i] = b;
        }
    }
    if (t == 255) bbase[NBKT] = part[255];
}

// ---- pass 2: chunked-reservation record scatter (4B records: local8|src18) ----
__global__ void scatter_records_kernel(const int* __restrict__ ei, int* __restrict__ bcur,
                                       int* __restrict__ rec) {
    __shared__ int lc[NBKT];
    for (int i = threadIdx.x; i < NBKT; i += 256) lc[i] = 0;
    __syncthreads();
    long e0 = (long)blockIdx.x * CHUNK;
    for (int k = threadIdx.x; k < CHUNK; k += 256) {
        long e = e0 + k;
        if (e < EE) {
            int u = ei[e], r = ei[EE + e];
            atomicAdd(&lc[r >> 8], 1);
            atomicAdd(&lc[NB_R + (u >> 8)], 1);
        }
    }
    __syncthreads();
    for (int i = threadIdx.x; i < NBKT; i += 256) {
        int c = lc[i];
        lc[i] = c ? atomicAdd(&bcur[i], c) : 0;   // reserve contiguous range
    }
    __syncthreads();
    for (int k = threadIdx.x; k < CHUNK; k += 256) {
        long e = e0 + k;
        if (e < EE) {
            int u = ei[e], r = ei[EE + e];
            int p1 = atomicAdd(&lc[r >> 8], 1);
            rec[p1] = ((r & 255) << 18) | u;
            int p2 = atomicAdd(&lc[NB_R + (u >> 8)], 1);
            rec[p2] = ((u & 255) << 18) | r;
        }
    }
}

// ---- pass 3: per-bucket counting sort -> adj (+ per-node base/cnt) ----
__global__ void build_adj_kernel(const int* __restrict__ rec, const int* __restrict__ bbase,
                                 int* __restrict__ adj, int* __restrict__ base,
                                 int* __restrict__ cnt) {
    __shared__ int c256[BKT];
    __shared__ int off256[BKT];
    int b = blockIdx.x;
    int s = bbase[b], e = bbase[b + 1];
    int t = threadIdx.x;
    c256[t] = 0;
    __syncthreads();
    for (int k = s + t; k < e; k += 256) atomicAdd(&c256[rec[k] >> 18], 1);
    __syncthreads();
    int v = c256[t];
    off256[t] = v;
    __syncthreads();
    for (int off = 1; off < 256; off <<= 1) {
        int x = (t >= off) ? off256[t - off] : 0;
        __syncthreads();
        off256[t] += x;
        __syncthreads();
    }
    int excl = off256[t] - v;
    bool isU = (b >= NB_R);
    int node = (isU ? (b - NB_R) : b) * BKT + t;
    int lim = isU ? NU : NR;
    if (node < lim) {
        int cid = isU ? (NR + node) : node;
        base[cid] = s + excl;
        cnt[cid] = v;
    }
    c256[t] = s + excl;    // cursors
    __syncthreads();
    for (int k = s + t; k < e; k += 256) {
        int rv = rec[k];
        int p = atomicAdd(&c256[rv >> 18], 1);
        adj[p] = rv & 0x3FFFF;
    }
}

// ---- node encoder: wave-per-row, weights in registers ----
template <int F>
__global__ __launch_bounds__(256, 2) void encode_kernel(
        const float* __restrict__ xin, const float* __restrict__ wT,
        const float* __restrict__ b, const float* __restrict__ emb,
        const int* __restrict__ nid, float* __restrict__ out, int N) {
    int t = threadIdx.x & 63;
    int wave = (int)((blockIdx.x * blockDim.x + threadIdx.x) >> 6);
    int nwaves = (gridDim.x * blockDim.x) >> 6;
    float wreg[F];
#pragma unroll
    for (int k = 0; k < F; ++k) wreg[k] = wT[k * Hc + t];
    float bv = b[t];
    for (int r = wave; r < N; r += nwaves) {
        float xv0 = (t < F) ? xin[(long)r * F + t] : 0.0f;
        float xv1 = (F > 64) ? xin[(long)r * F + 64 + t] : 0.0f;
        float acc = bv;
#pragma unroll
        for (int k = 0; k < F; ++k) {
            float s = (k < 64) ? rdlane(xv0, k) : rdlane(xv1, k - 64);
            acc = fmaf(s, wreg[k], acc);
        }
        acc += emb[(long)nid[r] * Hc + t];
        out[(long)r * Hc + t] = acc;
    }
}

// ---- fused SAGE: wave-per-row CSR gather + register matvec ----
__global__ __launch_bounds__(256, 2) void sage_kernel(
        const float* __restrict__ Xsrc, const float* __restrict__ Xdst,
        const int* __restrict__ base, const int* __restrict__ cnt,
        const int* __restrict__ adj, int nodeoff,
        const float* __restrict__ wlT, const float* __restrict__ bl,
        const float* __restrict__ wrT,
        float* __restrict__ out, int N, int relu) {
    int t = threadIdx.x & 63;
    int wave = (int)((blockIdx.x * blockDim.x + threadIdx.x) >> 6);
    int nwaves = (gridDim.x * blockDim.x) >> 6;
    float wl_[Hc], wr_[Hc];
#pragma unroll
    for (int k = 0; k < Hc; ++k) {
        wl_[k] = wlT[k * Hc + t];
        wr_[k] = wrT[k * Hc + t];
    }
    float bv = bl[t];
    for (int r = wave; r < N; r += nwaves) {
        int b0 = base[nodeoff + r], c = cnt[nodeoff + r];
        float s = 0.0f;
        int j = 0;
        for (; j + 4 <= c; j += 4) {
            int n0 = adj[b0 + j], n1 = adj[b0 + j + 1];
            int n2 = adj[b0 + j + 2], n3 = adj[b0 + j + 3];
            s += Xsrc[(long)n0 * Hc + t] + Xsrc[(long)n1 * Hc + t]
               + Xsrc[(long)n2 * Hc + t] + Xsrc[(long)n3 * Hc + t];
        }
        for (; j < c; ++j) s += Xsrc[(long)adj[b0 + j] * Hc + t];
        float msv = s / fmaxf((float)c, 1.0f);
        float xdv = Xdst[(long)r * Hc + t];
        float accl = bv, accr = 0.0f;
#pragma unroll
        for (int k = 0; k < Hc; ++k) {
            accl = fmaf(rdlane(msv, k), wl_[k], accl);
            accr = fmaf(rdlane(xdv, k), wr_[k], accr);
        }
        float o = accl + accr;
        if (relu) o = fmaxf(o, 0.0f);
        out[(long)r * Hc + t] = o;
    }
}

// ---- edge dot-product classifier ----
__global__ void edge_dot_kernel(const int* __restrict__ eli,
                                const float* __restrict__ HU2, const float* __restrict__ HR2,
                                float* __restrict__ out) {
    long gid = (long)blockIdx.x * blockDim.x + threadIdx.x;
    long e = gid >> 4;
    int t = (int)(gid & 15);
    if (e >= ELc) return;
    int a = eli[e], b = eli[ELc + e];
    float4 x = *(const float4*)(HU2 + (long)a * Hc + t * 4);
    float4 y = *(const float4*)(HR2 + (long)b * Hc + t * 4);
    float v = x.x * y.x + x.y * y.y + x.z * y.z + x.w * y.w;
    v += __shfl_xor(v, 1);
    v += __shfl_xor(v, 2);
    v += __shfl_xor(v, 4);
    v += __shfl_xor(v, 8);
    if (t == 0) out[e] = v;
}

extern "C" void kernel_launch(void* const* d_in, const int* in_sizes, int n_in,
                              void* d_out, int out_size, void* d_ws, size_t ws_size,
                              hipStream_t stream) {
    const float* x_user   = (const float*)d_in[0];
    const float* x_recipe = (const float*)d_in[1];
    const int*   user_nid = (const int*)d_in[2];
    const int*   rec_nid  = (const int*)d_in[3];
    const int*   edge_index = (const int*)d_in[4];
    const int*   edge_label = (const int*)d_in[5];
    const float* u_w   = (const float*)d_in[6];
    const float* u_b   = (const float*)d_in[7];
    const float* r_w   = (const float*)d_in[8];
    const float* r_b   = (const float*)d_in[9];
    const float* u_emb = (const float*)d_in[10];
    const float* r_emb = (const float*)d_in[11];
    const float* c1ra_wl = (const float*)d_in[12];
    const float* c1ra_bl = (const float*)d_in[13];
    const float* c1ra_wr = (const float*)d_in[14];
    const float* c1rv_wl = (const float*)d_in[15];
    const float* c1rv_bl = (const float*)d_in[16];
    const float* c1rv_wr = (const float*)d_in[17];
    const float* c2ra_wl = (const float*)d_in[18];
    const float* c2ra_bl = (const float*)d_in[19];
    const float* c2ra_wr = (const float*)d_in[20];
    const float* c2rv_wl = (const float*)d_in[21];
    const float* c2rv_bl = (const float*)d_in[22];
    const float* c2rv_wr = (const float*)d_in[23];

    float* ws = (float*)d_ws;
    const long NH = (long)NU * Hc;
    float* XU = ws;            // user enc; later reused for HR2
    float* XR = XU + NH;       // recipe enc; later reused for HU2
    float* HR = XR + NH;       // layer-1 recipe out; rec[] aliases here pre-layer-1
    float* HU = HR + NH;
    int* cnt   = (int*)(HU + NH);    // [NTOT]
    int* base  = cnt + NTOT;         // [NTOT]
    int* bcnt  = base + NTOT;        // [NBKT]
    int* bbase = bcnt + NBKT;        // [NBKT+1]
    int* bcur  = bbase + NBKT + 1;   // [NBKT]
    int* adj   = bcur + NBKT;        // [2*EE]
    float* wts = (float*)(adj + 2 * EE);
    float* uwT = wts;                // 58*64
    float* rwT = uwT + UF * Hc;      // 128*64
    float* cT[8];
    cT[0] = rwT + RF * Hc;
    for (int i = 1; i < 8; ++i) cT[i] = cT[i - 1] + Hc * Hc;
    int* rec = (int*)HR;             // 16MB alias, dead before layer 1

    // ---- weight transposes (once) ----
    TP10 tp;
    tp.m[0] = {u_w, uwT, UF};
    tp.m[1] = {r_w, rwT, RF};
    const float* srcs[8] = {c1ra_wl, c1ra_wr, c1rv_wl, c1rv_wr,
                            c2ra_wl, c2ra_wr, c2rv_wl, c2rv_wr};
    for (int i = 0; i < 8; ++i) tp.m[2 + i] = {srcs[i], cT[i], Hc};
    transpose_kernel<<<10, 256, 0, stream>>>(tp);

    // ---- CSR build via bucketed counting sort ----
    hipMemsetAsync(bcnt, 0, (size_t)NBKT * sizeof(int), stream);
    bucket_count_kernel<<<NCHUNK, 256, 0, stream>>>(edge_index, bcnt);
    bucket_scan_kernel<<<1, 256, 0, stream>>>(bcnt, bbase, bcur);
    scatter_records_kernel<<<NCHUNK, 256, 0, stream>>>(edge_index, bcur, rec);
    build_adj_kernel<<<NBKT, 256, 0, stream>>>(rec, bbase, adj, base, cnt);

    // ---- encoders ----
    encode_kernel<UF><<<2048, 256, 0, stream>>>(x_user, uwT, u_b, u_emb, user_nid, XU, NU);
    encode_kernel<RF><<<2048, 256, 0, stream>>>(x_recipe, rwT, r_b, r_emb, rec_nid, XR, NR);

    // ---- layer 1 ----
    sage_kernel<<<2048, 256, 0, stream>>>(XU, XR, base, cnt, adj, 0,  cT[0], c1ra_bl, cT[1], HR, NR, 1);
    sage_kernel<<<2048, 256, 0, stream>>>(XR, XU, base, cnt, adj, NR, cT[2], c1rv_bl, cT[3], HU, NU, 1);
    // ---- layer 2 ----
    sage_kernel<<<2048, 256, 0, stream>>>(HU, HR, base, cnt, adj, 0,  cT[4], c2ra_bl, cT[5], XU, NR, 0); // HR2
    sage_kernel<<<2048, 256, 0, stream>>>(HR, HU, base, cnt, adj, NR, cT[6], c2rv_bl, cT[7], XR, NU, 0); // HU2

    // ---- classifier: eli[0]=user -> HU2(XR), eli[1]=recipe -> HR2(XU) ----
    edge_dot_kernel<<<(ELc * 16) / 256, 256, 0, stream>>>(edge_label, XR, XU, (float*)d_out);
}

// Round 5
// 1176.369 us; speedup vs baseline: 6.7195x; 1.0088x over previous
//
#include <hip/hip_runtime.h>

constexpr int NU = 150000;
constexpr int NR = 150000;
constexpr int Hc = 64;
constexpr int UF = 58;
constexpr int RF = 128;
constexpr long EE = 2000000;
constexpr long ELc = 500000;
constexpr int NTOT = NU + NR;            // combined ids: [0,NR)=recipes, [NR,NTOT)=users
constexpr int BKT = 256;                 // nodes per bucket
constexpr int NB_R = (NR + BKT - 1) / BKT;   // 586
constexpr int NB_U = (NU + BKT - 1) / BKT;   // 586
constexpr int NBKT = NB_R + NB_U;            // 1172
constexpr int CHUNK = 4096;
constexpr int NCHUNK = (int)((EE + CHUNK - 1) / CHUNK);  // 489

__device__ inline float rdlane(float v, int l) {
    return __uint_as_float(__builtin_amdgcn_readlane(__float_as_uint(v), l));
}

// ---- weight pre-transpose: d[k*64+o] = s[o*F+k] (10 small matrices) ----
struct TP { const float* s; float* d; int F; };
struct TP10 { TP m[10]; };
__global__ void transpose_kernel(TP10 p) {
    TP t = p.m[blockIdx.x];
    for (int idx = threadIdx.x; idx < t.F * Hc; idx += blockDim.x) {
        int k = idx >> 6, o = idx & 63;
        t.d[idx] = t.s[o * t.F + k];
    }
}

// ---- CSR build, pass 0: per-bucket edge counts (LDS-binned) ----
__global__ void bucket_count_kernel(const int* __restrict__ ei, int* __restrict__ bcnt) {
    __shared__ int lc[NBKT];
    for (int i = threadIdx.x; i < NBKT; i += 256) lc[i] = 0;
    __syncthreads();
    long e0 = (long)blockIdx.x * CHUNK;
    for (int k = threadIdx.x; k < CHUNK; k += 256) {
        long e = e0 + k;
        if (e < EE) {
            int u = ei[e], r = ei[EE + e];
            atomicAdd(&lc[r >> 8], 1);
            atomicAdd(&lc[NB_R + (u >> 8)], 1);
        }
    }
    __syncthreads();
    for (int i = threadIdx.x; i < NBKT; i += 256)
        if (lc[i]) atomicAdd(&bcnt[i], lc[i]);
}

// ---- pass 1: exclusive scan over NBKT bucket counts (single block) ----
__global__ void bucket_scan_kernel(const int* __restrict__ bcnt, int* __restrict__ bbase,
                                   int* __restrict__ bcur) {
    __shared__ int part[256];
    constexpr int PER = (NBKT + 255) / 256;   // 5
    int t = threadIdx.x;
    int loc[PER];
    int sum = 0;
    for (int j = 0; j < PER; ++j) {
        int i = t * PER + j;
        int v = (i < NBKT) ? bcnt[i] : 0;
        loc[j] = sum;
        sum += v;
    }
    part[t] = sum;
    __syncthreads();
    for (int off = 1; off < 256; off <<= 1) {
        int v = (t >= off) ? part[t - off] : 0;
        __syncthreads();
        part[t] += v;
        __syncthreads();
    }
    int pre = (t == 0) ? 0 : part[t - 1];
    for (int j = 0; j < PER; ++j) {
        int i = t * PER + j;
        if (i < NBKT) {
            int b = pre + loc[j];
            bbase[i] = b;
            bcur[i] = b;
        }
    }
    if (t == 255) bbase[NBKT] = part[255];
}

// ---- pass 2: chunked-reservation record scatter (4B records: local8|src18) ----
__global__ void scatter_records_kernel(const int* __restrict__ ei, int* __restrict__ bcur,
                                       int* __restrict__ rec) {
    __shared__ int lc[NBKT];
    for (int i = threadIdx.x; i < NBKT; i += 256) lc[i] = 0;
    __syncthreads();
    long e0 = (long)blockIdx.x * CHUNK;
    for (int k = threadIdx.x; k < CHUNK; k += 256) {
        long e = e0 + k;
        if (e < EE) {
            int u = ei[e], r = ei[EE + e];
            atomicAdd(&lc[r >> 8], 1);
            atomicAdd(&lc[NB_R + (u >> 8)], 1);
        }
    }
    __syncthreads();
    for (int i = threadIdx.x; i < NBKT; i += 256) {
        int c = lc[i];
        lc[i] = c ? atomicAdd(&bcur[i], c) : 0;   // reserve contiguous range
    }
    __syncthreads();
    for (int k = threadIdx.x; k < CHUNK; k += 256) {
        long e = e0 + k;
        if (e < EE) {
            int u = ei[e], r = ei[EE + e];
            int p1 = atomicAdd(&lc[r >> 8], 1);
            rec[p1] = ((r & 255) << 18) | u;
            int p2 = atomicAdd(&lc[NB_R + (u >> 8)], 1);
            rec[p2] = ((u & 255) << 18) | r;
        }
    }
}

// ---- pass 3: per-bucket counting sort -> adj (+ per-node base/cnt) ----
__global__ void build_adj_kernel(const int* __restrict__ rec, const int* __restrict__ bbase,
                                 int* __restrict__ adj, int* __restrict__ base,
                                 int* __restrict__ cnt) {
    __shared__ int c256[BKT];
    __shared__ int off256[BKT];
    int b = blockIdx.x;
    int s = bbase[b], e = bbase[b + 1];
    int t = threadIdx.x;
    c256[t] = 0;
    __syncthreads();
    for (int k = s + t; k < e; k += 256) atomicAdd(&c256[rec[k] >> 18], 1);
    __syncthreads();
    int v = c256[t];
    off256[t] = v;
    __syncthreads();
    for (int off = 1; off < 256; off <<= 1) {
        int x = (t >= off) ? off256[t - off] : 0;
        __syncthreads();
        off256[t] += x;
        __syncthreads();
    }
    int excl = off256[t] - v;
    bool isU = (b >= NB_R);
    int node = (isU ? (b - NB_R) : b) * BKT + t;
    int lim = isU ? NU : NR;
    if (node < lim) {
        int cid = isU ? (NR + node) : node;
        base[cid] = s + excl;
        cnt[cid] = v;
    }
    c256[t] = s + excl;    // cursors
    __syncthreads();
    for (int k = s + t; k < e; k += 256) {
        int rv = rec[k];
        int p = atomicAdd(&c256[rv >> 18], 1);
        adj[p] = rv & 0x3FFFF;
    }
}

// ---- node encoder: weights staged in LDS (conflict-free), x broadcast via readlane ----
template <int F>
__global__ __launch_bounds__(256) void encode_kernel(
        const float* __restrict__ xin, const float* __restrict__ wT,
        const float* __restrict__ b, const float* __restrict__ emb,
        const int* __restrict__ nid, float* __restrict__ out, int N) {
    __shared__ float w[F * Hc];
    for (int idx = threadIdx.x; idx < F * Hc; idx += 256) w[idx] = wT[idx];
    __syncthreads();
    int t = threadIdx.x & 63;
    int wave = (int)((blockIdx.x * blockDim.x + threadIdx.x) >> 6);
    int nwaves = (gridDim.x * blockDim.x) >> 6;
    float bv = b[t];
    for (int r = wave; r < N; r += nwaves) {
        float xv0 = (t < F) ? xin[(long)r * F + t] : 0.0f;
        float xv1 = (F > 64) ? xin[(long)r * F + 64 + t] : 0.0f;
        float acc = bv;
#pragma unroll
        for (int k = 0; k < F; ++k) {
            float s = (k < 64) ? rdlane(xv0, k) : rdlane(xv1, k - 64);
            acc = fmaf(s, w[k * Hc + t], acc);
        }
        acc += emb[(long)nid[r] * Hc + t];
        out[(long)r * Hc + t] = acc;
    }
}

// ---- fused SAGE layer: both relations in one dispatch, block-partitioned.
//      Weights in LDS interleaved [k][0..63]=wl, [k][64..127]=wr (ds_read2-able).
__global__ __launch_bounds__(256) void sage_kernel(
        const float* __restrict__ Xu, const float* __restrict__ Xr,
        const int* __restrict__ base, const int* __restrict__ cnt,
        const int* __restrict__ adj,
        const float* __restrict__ wlTA, const float* __restrict__ blA,
        const float* __restrict__ wrTA,
        const float* __restrict__ wlTB, const float* __restrict__ blB,
        const float* __restrict__ wrTB,
        float* __restrict__ outR, float* __restrict__ outU, int relu) {
    __shared__ float w[Hc * 128];
    int half = gridDim.x >> 1;
    bool isU = blockIdx.x >= half;
    const float* wlT = isU ? wlTB : wlTA;
    const float* wrT = isU ? wrTB : wrTA;
    const float* bl  = isU ? blB : blA;
    const float* Xsrc = isU ? Xr : Xu;
    const float* Xdst = isU ? Xu : Xr;
    float* out = isU ? outU : outR;
    int N = isU ? NU : NR;
    int noff = isU ? NR : 0;
    for (int idx = threadIdx.x; idx < Hc * Hc; idx += 256) {
        int k = idx >> 6, o = idx & 63;
        w[k * 128 + o] = wlT[idx];
        w[k * 128 + 64 + o] = wrT[idx];
    }
    __syncthreads();
    int t = threadIdx.x & 63;
    int wid = (int)((((long)blockIdx.x - (isU ? half : 0)) * 256 + threadIdx.x) >> 6);
    int nw = (half * 256) >> 6;
    float bv = bl[t];
    for (int r = wid; r < N; r += nw) {
        int b0 = base[noff + r], c = cnt[noff + r];
        float s0 = 0.0f, s1 = 0.0f, s2 = 0.0f, s3 = 0.0f;
        int j = 0;
        for (; j + 8 <= c; j += 8) {
            int n0 = adj[b0 + j + 0], n1 = adj[b0 + j + 1];
            int n2 = adj[b0 + j + 2], n3 = adj[b0 + j + 3];
            int n4 = adj[b0 + j + 4], n5 = adj[b0 + j + 5];
            int n6 = adj[b0 + j + 6], n7 = adj[b0 + j + 7];
            s0 += Xsrc[(long)n0 * Hc + t]; s1 += Xsrc[(long)n1 * Hc + t];
            s2 += Xsrc[(long)n2 * Hc + t]; s3 += Xsrc[(long)n3 * Hc + t];
            s0 += Xsrc[(long)n4 * Hc + t]; s1 += Xsrc[(long)n5 * Hc + t];
            s2 += Xsrc[(long)n6 * Hc + t]; s3 += Xsrc[(long)n7 * Hc + t];
        }
        for (; j < c; ++j) s0 += Xsrc[(long)adj[b0 + j] * Hc + t];
        float s = (s0 + s1) + (s2 + s3);
        float msv = s / fmaxf((float)c, 1.0f);
        float xdv = Xdst[(long)r * Hc + t];
        float accl = bv, accr = 0.0f;
#pragma unroll
        for (int k = 0; k < Hc; ++k) {
            accl = fmaf(rdlane(msv, k), w[k * 128 + t], accl);
            accr = fmaf(rdlane(xdv, k), w[k * 128 + 64 + t], accr);
        }
        float o = accl + accr;
        if (relu) o = fmaxf(o, 0.0f);
        out[(long)r * Hc + t] = o;
    }
}

// ---- edge dot-product classifier ----
__global__ void edge_dot_kernel(const int* __restrict__ eli,
                                const float* __restrict__ HU2, const float* __restrict__ HR2,
                                float* __restrict__ out) {
    long gid = (long)blockIdx.x * blockDim.x + threadIdx.x;
    long e = gid >> 4;
    int t = (int)(gid & 15);
    if (e >= ELc) return;
    int a = eli[e], b = eli[ELc + e];
    float4 x = *(const float4*)(HU2 + (long)a * Hc + t * 4);
    float4 y = *(const float4*)(HR2 + (long)b * Hc + t * 4);
    float v = x.x * y.x + x.y * y.y + x.z * y.z + x.w * y.w;
    v += __shfl_xor(v, 1);
    v += __shfl_xor(v, 2);
    v += __shfl_xor(v, 4);
    v += __shfl_xor(v, 8);
    if (t == 0) out[e] = v;
}

extern "C" void kernel_launch(void* const* d_in, const int* in_sizes, int n_in,
                              void* d_out, int out_size, void* d_ws, size_t ws_size,
                              hipStream_t stream) {
    const float* x_user   = (const float*)d_in[0];
    const float* x_recipe = (const float*)d_in[1];
    const int*   user_nid = (const int*)d_in[2];
    const int*   rec_nid  = (const int*)d_in[3];
    const int*   edge_index = (const int*)d_in[4];
    const int*   edge_label = (const int*)d_in[5];
    const float* u_w   = (const float*)d_in[6];
    const float* u_b   = (const float*)d_in[7];
    const float* r_w   = (const float*)d_in[8];
    const float* r_b   = (const float*)d_in[9];
    const float* u_emb = (const float*)d_in[10];
    const float* r_emb = (const float*)d_in[11];
    const float* c1ra_wl = (const float*)d_in[12];
    const float* c1ra_bl = (const float*)d_in[13];
    const float* c1ra_wr = (const float*)d_in[14];
    const float* c1rv_wl = (const float*)d_in[15];
    const float* c1rv_bl = (const float*)d_in[16];
    const float* c1rv_wr = (const float*)d_in[17];
    const float* c2ra_wl = (const float*)d_in[18];
    const float* c2ra_bl = (const float*)d_in[19];
    const float* c2ra_wr = (const float*)d_in[20];
    const float* c2rv_wl = (const float*)d_in[21];
    const float* c2rv_bl = (const float*)d_in[22];
    const float* c2rv_wr = (const float*)d_in[23];

    float* ws = (float*)d_ws;
    const long NH = (long)NU * Hc;
    float* XU = ws;            // user enc; later reused for HR2
    float* XR = XU + NH;       // recipe enc; later reused for HU2
    float* HR = XR + NH;       // layer-1 recipe out; rec[] aliases here pre-layer-1
    float* HU = HR + NH;
    int* cnt   = (int*)(HU + NH);    // [NTOT]
    int* base  = cnt + NTOT;         // [NTOT]
    int* bcnt  = base + NTOT;        // [NBKT]
    int* bbase = bcnt + NBKT;        // [NBKT+1]
    int* bcur  = bbase + NBKT + 1;   // [NBKT]
    int* adj   = bcur + NBKT;        // [2*EE]
    float* wts = (float*)(adj + 2 * EE);
    float* uwT = wts;                // 58*64
    float* rwT = uwT + UF * Hc;      // 128*64
    float* cT[8];
    cT[0] = rwT + RF * Hc;
    for (int i = 1; i < 8; ++i) cT[i] = cT[i - 1] + Hc * Hc;
    int* rec = (int*)HR;             // 16MB alias, dead before layer 1

    // ---- weight transposes (once) ----
    TP10 tp;
    tp.m[0] = {u_w, uwT, UF};
    tp.m[1] = {r_w, rwT, RF};
    const float* srcs[8] = {c1ra_wl, c1ra_wr, c1rv_wl, c1rv_wr,
                            c2ra_wl, c2ra_wr, c2rv_wl, c2rv_wr};
    for (int i = 0; i < 8; ++i) tp.m[2 + i] = {srcs[i], cT[i], Hc};
    transpose_kernel<<<10, 256, 0, stream>>>(tp);

    // ---- CSR build via bucketed counting sort ----
    hipMemsetAsync(bcnt, 0, (size_t)NBKT * sizeof(int), stream);
    bucket_count_kernel<<<NCHUNK, 256, 0, stream>>>(edge_index, bcnt);
    bucket_scan_kernel<<<1, 256, 0, stream>>>(bcnt, bbase, bcur);
    scatter_records_kernel<<<NCHUNK, 256, 0, stream>>>(edge_index, bcur, rec);
    build_adj_kernel<<<NBKT, 256, 0, stream>>>(rec, bbase, adj, base, cnt);

    // ---- encoders ----
    encode_kernel<UF><<<2048, 256, 0, stream>>>(x_user, uwT, u_b, u_emb, user_nid, XU, NU);
    encode_kernel<RF><<<2048, 256, 0, stream>>>(x_recipe, rwT, r_b, r_emb, rec_nid, XR, NR);

    // ---- layer 1 (fused both relations; relu) ----
    sage_kernel<<<4096, 256, 0, stream>>>(XU, XR, base, cnt, adj,
                                          cT[0], c1ra_bl, cT[1],
                                          cT[2], c1rv_bl, cT[3],
                                          HR, HU, 1);
    // ---- layer 2 (outputs reuse XU/XR buffers) ----
    sage_kernel<<<4096, 256, 0, stream>>>(HU, HR, base, cnt, adj,
                                          cT[4], c2ra_bl, cT[5],
                                          cT[6], c2rv_bl, cT[7],
                                          XU, XR, 0);   // XU=HR2, XR=HU2

    // ---- classifier: eli[0]=user -> HU2(XR), eli[1]=recipe -> HR2(XU) ----
    edge_dot_kernel<<<(ELc * 16) / 256, 256, 0, stream>>>(edge_label, XR, XU, (float*)d_out);
}

// Round 6
// 976.492 us; speedup vs baseline: 8.0950x; 1.2047x over previous
//
#include <hip/hip_runtime.h>

constexpr int NU = 150000;
constexpr int NR = 150000;
constexpr int Hc = 64;
constexpr int UF = 58;
constexpr int RF = 128;
constexpr long EE = 2000000;
constexpr long ELc = 500000;
constexpr int NTOT = NU + NR;            // combined ids: [0,NR)=recipes, [NR,NTOT)=users
constexpr int BKT = 256;                 // nodes per bucket
constexpr int NB_R = (NR + BKT - 1) / BKT;   // 586
constexpr int NB_U = (NU + BKT - 1) / BKT;   // 586
constexpr int NBKT = NB_R + NB_U;            // 1172
constexpr int CHUNK = 4096;
constexpr int NCHUNK = (int)((EE + CHUNK - 1) / CHUNK);  // 489

__device__ inline float rdlane(float v, int l) {
    return __uint_as_float(__builtin_amdgcn_readlane(__float_as_uint(v), l));
}

// ---- weight pre-transpose: d[k*64+o] = s[o*F+k] (10 small matrices) ----
struct TP { const float* s; float* d; int F; };
struct TP10 { TP m[10]; };
__global__ void transpose_kernel(TP10 p) {
    TP t = p.m[blockIdx.x];
    for (int idx = threadIdx.x; idx < t.F * Hc; idx += blockDim.x) {
        int k = idx >> 6, o = idx & 63;
        t.d[idx] = t.s[o * t.F + k];
    }
}

// ---- CSR build, pass 0: per-bucket edge counts (LDS-binned) ----
__global__ void bucket_count_kernel(const int* __restrict__ ei, int* __restrict__ bcnt) {
    __shared__ int lc[NBKT];
    for (int i = threadIdx.x; i < NBKT; i += 256) lc[i] = 0;
    __syncthreads();
    long e0 = (long)blockIdx.x * CHUNK;
    for (int k = threadIdx.x; k < CHUNK; k += 256) {
        long e = e0 + k;
        if (e < EE) {
            int u = ei[e], r = ei[EE + e];
            atomicAdd(&lc[r >> 8], 1);
            atomicAdd(&lc[NB_R + (u >> 8)], 1);
        }
    }
    __syncthreads();
    for (int i = threadIdx.x; i < NBKT; i += 256)
        if (lc[i]) atomicAdd(&bcnt[i], lc[i]);
}

// ---- pass 1: exclusive scan over NBKT bucket counts (single block) ----
__global__ void bucket_scan_kernel(const int* __restrict__ bcnt, int* __restrict__ bbase,
                                   int* __restrict__ bcur) {
    __shared__ int part[256];
    constexpr int PER = (NBKT + 255) / 256;   // 5
    int t = threadIdx.x;
    int loc[PER];
    int sum = 0;
    for (int j = 0; j < PER; ++j) {
        int i = t * PER + j;
        int v = (i < NBKT) ? bcnt[i] : 0;
        loc[j] = sum;
        sum += v;
    }
    part[t] = sum;
    __syncthreads();
    for (int off = 1; off < 256; off <<= 1) {
        int v = (t >= off) ? part[t - off] : 0;
        __syncthreads();
        part[t] += v;
        __syncthreads();
    }
    int pre = (t == 0) ? 0 : part[t - 1];
    for (int j = 0; j < PER; ++j) {
        int i = t * PER + j;
        if (i < NBKT) {
            int b = pre + loc[j];
            bbase[i] = b;
            bcur[i] = b;
        }
    }
    if (t == 255) bbase[NBKT] = part[255];
}

// ---- pass 2: chunked-reservation record scatter (4B records: local8|src18) ----
__global__ void scatter_records_kernel(const int* __restrict__ ei, int* __restrict__ bcur,
                                       int* __restrict__ rec) {
    __shared__ int lc[NBKT];
    for (int i = threadIdx.x; i < NBKT; i += 256) lc[i] = 0;
    __syncthreads();
    long e0 = (long)blockIdx.x * CHUNK;
    for (int k = threadIdx.x; k < CHUNK; k += 256) {
        long e = e0 + k;
        if (e < EE) {
            int u = ei[e], r = ei[EE + e];
            atomicAdd(&lc[r >> 8], 1);
            atomicAdd(&lc[NB_R + (u >> 8)], 1);
        }
    }
    __syncthreads();
    for (int i = threadIdx.x; i < NBKT; i += 256) {
        int c = lc[i];
        lc[i] = c ? atomicAdd(&bcur[i], c) : 0;   // reserve contiguous range
    }
    __syncthreads();
    for (int k = threadIdx.x; k < CHUNK; k += 256) {
        long e = e0 + k;
        if (e < EE) {
            int u = ei[e], r = ei[EE + e];
            int p1 = atomicAdd(&lc[r >> 8], 1);
            rec[p1] = ((r & 255) << 18) | u;
            int p2 = atomicAdd(&lc[NB_R + (u >> 8)], 1);
            rec[p2] = ((u & 255) << 18) | r;
        }
    }
}

// ---- pass 3: per-bucket counting sort -> adj (+ per-node base/cnt) ----
__global__ void build_adj_kernel(const int* __restrict__ rec, const int* __restrict__ bbase,
                                 int* __restrict__ adj, int* __restrict__ base,
                                 int* __restrict__ cnt) {
    __shared__ int c256[BKT];
    __shared__ int off256[BKT];
    int b = blockIdx.x;
    int s = bbase[b], e = bbase[b + 1];
    int t = threadIdx.x;
    c256[t] = 0;
    __syncthreads();
    for (int k = s + t; k < e; k += 256) atomicAdd(&c256[rec[k] >> 18], 1);
    __syncthreads();
    int v = c256[t];
    off256[t] = v;
    __syncthreads();
    for (int off = 1; off < 256; off <<= 1) {
        int x = (t >= off) ? off256[t - off] : 0;
        __syncthreads();
        off256[t] += x;
        __syncthreads();
    }
    int excl = off256[t] - v;
    bool isU = (b >= NB_R);
    int node = (isU ? (b - NB_R) : b) * BKT + t;
    int lim = isU ? NU : NR;
    if (node < lim) {
        int cid = isU ? (NR + node) : node;
        base[cid] = s + excl;
        cnt[cid] = v;
    }
    c256[t] = s + excl;    // cursors
    __syncthreads();
    for (int k = s + t; k < e; k += 256) {
        int rv = rec[k];
        int p = atomicAdd(&c256[rv >> 18], 1);
        adj[p] = rv & 0x3FFFF;
    }
}

// ---- node encoder: weights staged in LDS (conflict-free), x broadcast via readlane ----
template <int F>
__global__ __launch_bounds__(256) void encode_kernel(
        const float* __restrict__ xin, const float* __restrict__ wT,
        const float* __restrict__ b, const float* __restrict__ emb,
        const int* __restrict__ nid, float* __restrict__ out, int N) {
    __shared__ float w[F * Hc];
    for (int idx = threadIdx.x; idx < F * Hc; idx += 256) w[idx] = wT[idx];
    __syncthreads();
    int t = threadIdx.x & 63;
    int wave = (int)((blockIdx.x * blockDim.x + threadIdx.x) >> 6);
    int nwaves = (gridDim.x * blockDim.x) >> 6;
    float bv = b[t];
    for (int r = wave; r < N; r += nwaves) {
        float xv0 = (t < F) ? xin[(long)r * F + t] : 0.0f;
        float xv1 = (F > 64) ? xin[(long)r * F + 64 + t] : 0.0f;
        float acc = bv;
#pragma unroll
        for (int k = 0; k < F; ++k) {
            float s = (k < 64) ? rdlane(xv0, k) : rdlane(xv1, k - 64);
            acc = fmaf(s, w[k * Hc + t], acc);
        }
        acc += emb[(long)nid[r] * Hc + t];
        out[(long)r * Hc + t] = acc;
    }
}

// ---- dense dual-matvec: outA = in@wA^T (no bias); outB = in@wB^T + bB.
//      outA may alias `in` (each row fully read before written). ----
__global__ __launch_bounds__(256) void dense2_kernel(
        const float* in, const float* wAT, float* outA,
        const float* wBT, const float* bB, float* outB, int N) {
    __shared__ float w[Hc * 128];   // interleaved: [k][0..63]=wA, [k][64..127]=wB
    for (int idx = threadIdx.x; idx < Hc * Hc; idx += 256) {
        int k = idx >> 6, o = idx & 63;
        w[k * 128 + o] = wAT[idx];
        w[k * 128 + 64 + o] = wBT[idx];
    }
    __syncthreads();
    int t = threadIdx.x & 63;
    int wid = (int)((blockIdx.x * blockDim.x + threadIdx.x) >> 6);
    int nw = (gridDim.x * blockDim.x) >> 6;
    float bv = bB[t];
    for (int r = wid; r < N; r += nw) {
        float xv = in[(long)r * Hc + t];
        float accA = 0.0f, accB = bv;
#pragma unroll
        for (int k = 0; k < Hc; ++k) {
            float s = rdlane(xv, k);
            accA = fmaf(s, w[k * 128 + t], accA);
            accB = fmaf(s, w[k * 128 + 64 + t], accB);
        }
        outA[(long)r * Hc + t] = accA;
        outB[(long)r * Hc + t] = accB;
    }
}

// ---- pure-memory gather: io[r] = maybe_relu(io[r] + mean of T rows) ----
__global__ __launch_bounds__(256) void gather_kernel(
        const float* __restrict__ T, float* __restrict__ io,
        const int* __restrict__ base, const int* __restrict__ cnt,
        const int* __restrict__ adj, int noff, int N, int relu) {
    int t = threadIdx.x & 63;
    int r = (int)(((long)blockIdx.x * blockDim.x + threadIdx.x) >> 6);
    if (r >= N) return;
    int b0 = base[noff + r], c = cnt[noff + r];
    float s0 = 0.0f, s1 = 0.0f, s2 = 0.0f, s3 = 0.0f;
    int j = 0;
    for (; j + 8 <= c; j += 8) {
        int n0 = adj[b0 + j + 0], n1 = adj[b0 + j + 1];
        int n2 = adj[b0 + j + 2], n3 = adj[b0 + j + 3];
        int n4 = adj[b0 + j + 4], n5 = adj[b0 + j + 5];
        int n6 = adj[b0 + j + 6], n7 = adj[b0 + j + 7];
        s0 += T[(long)n0 * Hc + t]; s1 += T[(long)n1 * Hc + t];
        s2 += T[(long)n2 * Hc + t]; s3 += T[(long)n3 * Hc + t];
        s0 += T[(long)n4 * Hc + t]; s1 += T[(long)n5 * Hc + t];
        s2 += T[(long)n6 * Hc + t]; s3 += T[(long)n7 * Hc + t];
    }
    for (; j < c; ++j) s0 += T[(long)adj[b0 + j] * Hc + t];
    float s = (s0 + s1) + (s2 + s3);
    float o = io[(long)r * Hc + t] + s / fmaxf((float)c, 1.0f);
    if (relu) o = fmaxf(o, 0.0f);
    io[(long)r * Hc + t] = o;
}

// ---- edge dot-product classifier ----
__global__ void edge_dot_kernel(const int* __restrict__ eli,
                                const float* __restrict__ HU2, const float* __restrict__ HR2,
                                float* __restrict__ out) {
    long gid = (long)blockIdx.x * blockDim.x + threadIdx.x;
    long e = gid >> 4;
    int t = (int)(gid & 15);
    if (e >= ELc) return;
    int a = eli[e], b = eli[ELc + e];
    float4 x = *(const float4*)(HU2 + (long)a * Hc + t * 4);
    float4 y = *(const float4*)(HR2 + (long)b * Hc + t * 4);
    float v = x.x * y.x + x.y * y.y + x.z * y.z + x.w * y.w;
    v += __shfl_xor(v, 1);
    v += __shfl_xor(v, 2);
    v += __shfl_xor(v, 4);
    v += __shfl_xor(v, 8);
    if (t == 0) out[e] = v;
}

extern "C" void kernel_launch(void* const* d_in, const int* in_sizes, int n_in,
                              void* d_out, int out_size, void* d_ws, size_t ws_size,
                              hipStream_t stream) {
    const float* x_user   = (const float*)d_in[0];
    const float* x_recipe = (const float*)d_in[1];
    const int*   user_nid = (const int*)d_in[2];
    const int*   rec_nid  = (const int*)d_in[3];
    const int*   edge_index = (const int*)d_in[4];
    const int*   edge_label = (const int*)d_in[5];
    const float* u_w   = (const float*)d_in[6];
    const float* u_b   = (const float*)d_in[7];
    const float* r_w   = (const float*)d_in[8];
    const float* r_b   = (const float*)d_in[9];
    const float* u_emb = (const float*)d_in[10];
    const float* r_emb = (const float*)d_in[11];
    const float* c1ra_wl = (const float*)d_in[12];
    const float* c1ra_bl = (const float*)d_in[13];
    const float* c1ra_wr = (const float*)d_in[14];
    const float* c1rv_wl = (const float*)d_in[15];
    const float* c1rv_bl = (const float*)d_in[16];
    const float* c1rv_wr = (const float*)d_in[17];
    const float* c2ra_wl = (const float*)d_in[18];
    const float* c2ra_bl = (const float*)d_in[19];
    const float* c2ra_wr = (const float*)d_in[20];
    const float* c2rv_wl = (const float*)d_in[21];
    const float* c2rv_bl = (const float*)d_in[22];
    const float* c2rv_wr = (const float*)d_in[23];

    float* ws = (float*)d_ws;
    const long NH = (long)NU * Hc;
    float* B0 = ws;            // XU -> TU1 (in-place) -> PRE_U2 -> HU2
    float* B1 = B0 + NH;       // XR -> TR1 (in-place) -> PRE_R2 -> HR2
    float* B2 = B1 + NH;       // PRE_U -> HU -> TU2 (in-place); rec[] aliases pre-encode
    float* B3 = B2 + NH;       // PRE_R -> HR -> TR2 (in-place)
    int* cnt   = (int*)(B3 + NH);    // [NTOT]
    int* base  = cnt + NTOT;         // [NTOT]
    int* bcnt  = base + NTOT;        // [NBKT]
    int* bbase = bcnt + NBKT;        // [NBKT+1]
    int* bcur  = bbase + NBKT + 1;   // [NBKT]
    int* adj   = bcur + NBKT;        // [2*EE]
    float* wts = (float*)(adj + 2 * EE);
    float* uwT = wts;                // 58*64
    float* rwT = uwT + UF * Hc;      // 128*64
    float* cT[8];
    cT[0] = rwT + RF * Hc;
    for (int i = 1; i < 8; ++i) cT[i] = cT[i - 1] + Hc * Hc;
    int* rec = (int*)B2;             // 16MB alias, dead before first B2 write

    // ---- weight transposes (once) ----
    TP10 tp;
    tp.m[0] = {u_w, uwT, UF};
    tp.m[1] = {r_w, rwT, RF};
    const float* srcs[8] = {c1ra_wl, c1ra_wr, c1rv_wl, c1rv_wr,
                            c2ra_wl, c2ra_wr, c2rv_wl, c2rv_wr};
    for (int i = 0; i < 8; ++i) tp.m[2 + i] = {srcs[i], cT[i], Hc};
    transpose_kernel<<<10, 256, 0, stream>>>(tp);

    // ---- CSR build via bucketed counting sort ----
    hipMemsetAsync(bcnt, 0, (size_t)NBKT * sizeof(int), stream);
    bucket_count_kernel<<<NCHUNK, 256, 0, stream>>>(edge_index, bcnt);
    bucket_scan_kernel<<<1, 256, 0, stream>>>(bcnt, bbase, bcur);
    scatter_records_kernel<<<NCHUNK, 256, 0, stream>>>(edge_index, bcur, rec);
    build_adj_kernel<<<NBKT, 256, 0, stream>>>(rec, bbase, adj, base, cnt);

    // ---- encoders ----
    encode_kernel<UF><<<2048, 256, 0, stream>>>(x_user, uwT, u_b, u_emb, user_nid, B0, NU);
    encode_kernel<RF><<<2048, 256, 0, stream>>>(x_recipe, rwT, r_b, r_emb, rec_nid, B1, NR);

    const int GG = (NU * 64 + 255) / 256;   // exact wave-per-row grid (37500)
    // ---- layer 1: transform-then-mean ----
    // TU1 = XU@c1ra_wl (in-place B0); PRE_U = XU@c1rv_wr + c1rv_bl -> B2
    dense2_kernel<<<2048, 256, 0, stream>>>(B0, cT[0], B0, cT[3], c1rv_bl, B2, NU);
    // TR1 = XR@c1rv_wl (in-place B1); PRE_R = XR@c1ra_wr + c1ra_bl -> B3
    dense2_kernel<<<2048, 256, 0, stream>>>(B1, cT[2], B1, cT[1], c1ra_bl, B3, NR);
    // HR = relu(PRE_R + mean of TU1 rows)    [recipe side: noff=0]
    gather_kernel<<<GG, 256, 0, stream>>>(B0, B3, base, cnt, adj, 0, NR, 1);
    // HU = relu(PRE_U + mean of TR1 rows)    [user side: noff=NR]
    gather_kernel<<<GG, 256, 0, stream>>>(B1, B2, base, cnt, adj, NR, NU, 1);

    // ---- layer 2 ----
    // TU2 = HU@c2ra_wl (in-place B2); PRE_U2 = HU@c2rv_wr + c2rv_bl -> B0
    dense2_kernel<<<2048, 256, 0, stream>>>(B2, cT[4], B2, cT[7], c2rv_bl, B0, NU);
    // TR2 = HR@c2rv_wl (in-place B3); PRE_R2 = HR@c2ra_wr + c2ra_bl -> B1
    dense2_kernel<<<2048, 256, 0, stream>>>(B3, cT[6], B3, cT[5], c2ra_bl, B1, NR);
    // HR2 = PRE_R2 + mean(TU2 rows)  -> B1
    gather_kernel<<<GG, 256, 0, stream>>>(B2, B1, base, cnt, adj, 0, NR, 0);
    // HU2 = PRE_U2 + mean(TR2 rows)  -> B0
    gather_kernel<<<GG, 256, 0, stream>>>(B3, B0, base, cnt, adj, NR, NU, 0);

    // ---- classifier: eli[0]=user -> HU2(B0), eli[1]=recipe -> HR2(B1) ----
    edge_dot_kernel<<<(ELc * 16) / 256, 256, 0, stream>>>(edge_label, B0, B1, (float*)d_out);
}